// Round 10
// baseline (512.493 us; speedup 1.0000x reference)
//
#include <hip/hip_runtime.h>
#include <math.h>

#define BB 4
#define HH 4
#define NN 2048
#define DD 256
#define HDIM 64
#define NTOK 8192
#define NTOK2 16384

typedef __attribute__((ext_vector_type(8))) __bf16 bf16x8;
typedef __attribute__((ext_vector_type(8))) unsigned short ushort8;
typedef __attribute__((ext_vector_type(4))) float floatx4;
typedef __attribute__((ext_vector_type(4))) short short4v;

union U8 { ushort8 u; bf16x8 b; };
union U4 { unsigned int u[2]; unsigned long long l; short4v s; };

// v_mfma_f32_16x16x16_bf16 (K=16): A/B = 4 bf16 (short4), C/D = 4 f32.
#define MFMA16(a, b, c) __builtin_amdgcn_mfma_f32_16x16x16bf16_1k(a, b, c, 0, 0, 0)

__device__ __forceinline__ unsigned short f2bf(float x) {
    unsigned int u = __float_as_uint(x);
    u += 0x7FFF + ((u >> 16) & 1);
    return (unsigned short)(u >> 16);
}
__device__ __forceinline__ float bf2f(unsigned short u) {
    return __uint_as_float(((unsigned int)u) << 16);
}
// round-half-up bf16 pair pack (a -> low16, b -> high16); inputs >= 0
__device__ __forceinline__ unsigned int pkbf(float a, float b) {
    return ((__float_as_uint(a) + 0x8000u) >> 16) |
           ((__float_as_uint(b) + 0x8000u) & 0xFFFF0000u);
}

// ---------------------------------------------------------------------------
// Weight transpose+convert: W[K][N] f32 -> Wt[n'][st] bf16.
// pm=1 (qkv): output row n' = (n%3)*256 + n/3  (Q|K|V contiguous, (h,d) order)
// ---------------------------------------------------------------------------
struct WTab {
    const float* w[7];
    unsigned short* o[7];
    int K[7];
    int N[7];
    int st[7];
    int pm[7];
    int t0[8];
};

__global__ __launch_bounds__(256) void wtrans(WTab tab)
{
    __shared__ float lds[32][33];
    const int t = threadIdx.x;
    int bid = blockIdx.x;
    int s = 0;
    while (bid >= tab.t0[s + 1]) s++;
    const int ti = bid - tab.t0[s];
    const int K = tab.K[s], N = tab.N[s], st = tab.st[s], pm = tab.pm[s];
    const int tx = ti % (N / 32), ty = ti / (N / 32);
    const int k0 = ty * 32, n0 = tx * 32;
    const float* W = tab.w[s];
    unsigned short* Wt = tab.o[s];

    {
        int r = t >> 3, c = (t & 7) * 4;
        float4 a = *(const float4*)&W[(size_t)(k0 + r) * N + n0 + c];
        lds[r][c] = a.x; lds[r][c+1] = a.y; lds[r][c+2] = a.z; lds[r][c+3] = a.w;
    }
    __syncthreads();
    {
        int n = t >> 3, kq = (t & 7) * 4;
        ushort4 p;
        p.x = f2bf(lds[kq+0][n]); p.y = f2bf(lds[kq+1][n]);
        p.z = f2bf(lds[kq+2][n]); p.w = f2bf(lds[kq+3][n]);
        int na = n0 + n;
        int row = pm ? ((na % 3) * 256 + na / 3) : na;
        *(ushort4*)&Wt[(size_t)row * st + k0 + kq] = p;
    }
}

// ---------------------------------------------------------------------------
// Weight fusion: Weff_bot[i][n] = sum_j Wo[i][j] * W1[256+j][n], transposed
// bf16 into out[n][256+i] (512-stride).  grid 128: seg = bid>>6.
// ---------------------------------------------------------------------------
__global__ __launch_bounds__(256) void wfuse(
    const float* __restrict__ Wo_s, const float* __restrict__ W1_s,
    unsigned short* __restrict__ o_s,
    const float* __restrict__ Wo_c, const float* __restrict__ W1_c,
    unsigned short* __restrict__ o_c)
{
    __shared__ float wo[32][33];
    __shared__ float w1[32][68];
    const int t = threadIdx.x;
    const int bid = blockIdx.x;
    const int seg = bid >> 6, ti_ = bid & 63;
    const int i0 = (ti_ >> 3) * 32, n0 = (ti_ & 7) * 64;
    const float* Wo  = seg ? Wo_c : Wo_s;
    const float* W1b = (seg ? W1_c : W1_s) + 256 * 512;
    unsigned short* out = seg ? o_c : o_s;
    const int ti = t >> 3, tn = t & 7;

    float acc[8] = {};
    for (int jc = 0; jc < 256; jc += 32) {
        {
            int r = t >> 3, c = (t & 7) * 4;
            *(float4*)&wo[r][c] = *(const float4*)&Wo[(size_t)(i0 + r) * 256 + jc + c];
            int c8 = (t & 7) * 8;
            *(float4*)&w1[r][c8]     = *(const float4*)&W1b[(size_t)(jc + r) * 512 + n0 + c8];
            *(float4*)&w1[r][c8 + 4] = *(const float4*)&W1b[(size_t)(jc + r) * 512 + n0 + c8 + 4];
        }
        __syncthreads();
        #pragma unroll
        for (int j = 0; j < 32; j++) {
            float a = wo[ti][j];
            #pragma unroll
            for (int e = 0; e < 8; e++) acc[e] += a * w1[j][tn * 8 + e];
        }
        __syncthreads();
    }
    #pragma unroll
    for (int e = 0; e < 8; e++)
        out[(size_t)(n0 + tn * 8 + e) * 512 + 256 + i0 + ti] = f2bf(acc[e]);
}

// ---------------------------------------------------------------------------
// Bias fusion: beff[n] = b1[n] + sum_j bo[j] * W1[256+j][n].  grid 4.
// ---------------------------------------------------------------------------
__global__ __launch_bounds__(256) void bfuse(
    const float* bo_s, const float* W1_s, const float* b1_s, float* bs,
    const float* bo_c, const float* W1_c, const float* b1_c, float* bc)
{
    const int seg = blockIdx.x >> 1, half = blockIdx.x & 1;
    const int n = half * 256 + threadIdx.x;
    const float* bo  = seg ? bo_c : bo_s;
    const float* W1b = (seg ? W1_c : W1_s) + 256 * 512;
    const float* b1  = seg ? b1_c : b1_s;
    float* out       = seg ? bc : bs;
    float a = b1[n];
    for (int j = 0; j < 256; j++) a += bo[j] * W1b[(size_t)j * 512 + n];
    out[n] = a;
}

// ---------------------------------------------------------------------------
// bf16 MFMA GEMM, 128x128 tile, reg-prefetch double-buffer, rows padded 40.
// C[m][n] = sum_k A[m][k]*B[n][k] + bias.
// modes: 0 V^T (A=weights rows=hd, cols=tok): o0[((bh)*64+d)*2048+n],
//          bias[grow*bmul + bmul-1]
//        1 bf16 row-major o0[grow*ldc+col]
//        5 self QK scatter + fused RoPE: sel=col>>8 (0=Q->o0,1=K->o1),
//          bias[(col&255)*3+sel], store [bh][n][d]
//        6 cross QK scatter: bias[col&255], store o0 [bh][n][d]
// ---------------------------------------------------------------------------
__global__ __launch_bounds__(256) void gemm128(
    const unsigned short* __restrict__ A, int lda,
    const unsigned short* __restrict__ B, int ldb, int K,
    const float* __restrict__ bias, int mode, int bmul,
    unsigned short* o0, unsigned short* o1, int ldc,
    const float* __restrict__ e0g, const float* __restrict__ e1g)
{
    __shared__ __align__(16) unsigned short As[128 * 40];
    __shared__ __align__(16) unsigned short Bs[128 * 40];
    const int t = threadIdx.x;
    const int w = t >> 6, lane = t & 63, quad = lane >> 4, l15 = lane & 15;
    const int m0 = blockIdx.y * 128, n0 = blockIdx.x * 128;
    const int wm = (w >> 1) * 64, wn = (w & 1) * 64;
    const int sr = t >> 1, sc = (t & 1) * 16;

    const unsigned short* Ap = A + (size_t)(m0 + sr) * lda + sc;
    const unsigned short* Bp = B + (size_t)(n0 + sr) * ldb + sc;

    ushort8 pa0 = *(const ushort8*)(Ap);
    ushort8 pa1 = *(const ushort8*)(Ap + 8);
    ushort8 pb0 = *(const ushort8*)(Bp);
    ushort8 pb1 = *(const ushort8*)(Bp + 8);

    floatx4 acc[4][4];
    #pragma unroll
    for (int i = 0; i < 4; i++)
        #pragma unroll
        for (int j = 0; j < 4; j++) acc[i][j] = (floatx4){0.f, 0.f, 0.f, 0.f};

    const int nk = K >> 5;
    for (int kk = 0; kk < nk; kk++) {
        *(ushort8*)&As[sr * 40 + sc]     = pa0;
        *(ushort8*)&As[sr * 40 + sc + 8] = pa1;
        *(ushort8*)&Bs[sr * 40 + sc]     = pb0;
        *(ushort8*)&Bs[sr * 40 + sc + 8] = pb1;
        __syncthreads();
        if (kk + 1 < nk) {
            int ko = (kk + 1) * 32;
            pa0 = *(const ushort8*)(Ap + ko);
            pa1 = *(const ushort8*)(Ap + ko + 8);
            pb0 = *(const ushort8*)(Bp + ko);
            pb1 = *(const ushort8*)(Bp + ko + 8);
        }
        U8 af[4], bf[4];
        #pragma unroll
        for (int i = 0; i < 4; i++)
            af[i].u = *(const ushort8*)&As[(wm + i * 16 + l15) * 40 + quad * 8];
        #pragma unroll
        for (int j = 0; j < 4; j++)
            bf[j].u = *(const ushort8*)&Bs[(wn + j * 16 + l15) * 40 + quad * 8];
        #pragma unroll
        for (int i = 0; i < 4; i++)
            #pragma unroll
            for (int j = 0; j < 4; j++)
                acc[i][j] = __builtin_amdgcn_mfma_f32_16x16x32_bf16(af[i].b, bf[j].b, acc[i][j], 0, 0, 0);
        __syncthreads();
    }

    #pragma unroll
    for (int i = 0; i < 4; i++) {
        #pragma unroll
        for (int j = 0; j < 4; j++) {
            int col = n0 + wn + j * 16 + l15;
            float bv = 0.f;
            if (mode == 5)      bv = bias[(col & 255) * 3 + (col >> 8)];
            else if (mode == 6) bv = bias[col & 255];
            else if (mode == 1) bv = bias[col];
            #pragma unroll
            for (int r = 0; r < 4; r++) {
                int grow = m0 + wm + i * 16 + quad * 4 + r;
                float v = acc[i][j][r] + bv;
                if (mode == 1) {
                    o0[(size_t)grow * ldc + col] = f2bf(v);
                } else if (mode == 0) {
                    float vv = acc[i][j][r] + bias[grow * bmul + (bmul - 1)];
                    int h = (grow >> 6) & 3, d = grow & 63;
                    int ds = col >> 13, b = (col >> 11) & 3, n = col & 2047;
                    o0[((size_t)((ds * 16 + b * 4 + h) * 64 + d)) * 2048 + n] = f2bf(vv);
                } else if (mode == 5) {
                    int sel = col >> 8, cc = col & 255;
                    int h = cc >> 6, d = cc & 63;
                    int ds = grow >> 13, b = (grow >> 11) & 3, n = grow & 2047;
                    const float* eb = (ds ? e1g : e0g) + ((size_t)(b * 2048 + n)) * 64 + d;
                    float p = __shfl_xor(v, 1, 64);
                    float f0 = eb[0], f1 = eb[524288];
                    float y = v * f0 + ((d & 1) ? p : -p) * f1;
                    unsigned short* dst = sel ? o1 : o0;
                    dst[(((size_t)(ds * 16 + b * 4 + h)) * 2048 + n) * 64 + d] = f2bf(y);
                } else {  // mode 6
                    int cc = col & 255;
                    int h = cc >> 6, d = cc & 63;
                    int ds = grow >> 13, b = (grow >> 11) & 3, n = grow & 2047;
                    o0[(((size_t)(ds * 16 + b * 4 + h)) * 2048 + n) * 64 + d] = f2bf(v);
                }
            }
        }
    }
}

// ---------------------------------------------------------------------------
// W2 GEMM: 64x128 tile, K=512, f32 out = acc + bias + residual, plus bf16
// copies (outH0 stride 256, outH1 stride 512 left-half of next concat).
// ---------------------------------------------------------------------------
__global__ __launch_bounds__(256) void gemm_w2(
    const unsigned short* __restrict__ A,
    const unsigned short* __restrict__ Wt,
    const float* __restrict__ bias,
    float* outF, unsigned short* outH0, unsigned short* outH1,
    const float* R0, const float* R1)
{
    __shared__ __align__(16) unsigned short As[64 * 40];
    __shared__ __align__(16) unsigned short Bs[128 * 40];
    const int t = threadIdx.x;
    const int w = t >> 6, lane = t & 63, quad = lane >> 4, l15 = lane & 15;
    const int m0 = blockIdx.y * 64, n0 = blockIdx.x * 128;
    const int wn = w * 32;
    const int sar = t >> 2, sac = (t & 3) * 8;
    const int sbr = t >> 1, sbc = (t & 1) * 16;
    const int K = 512;

    const unsigned short* Ap = A  + (size_t)(m0 + sar) * 512 + sac;
    const unsigned short* Bp = Wt + (size_t)(n0 + sbr) * K   + sbc;

    ushort8 pa  = *(const ushort8*)(Ap);
    ushort8 pb0 = *(const ushort8*)(Bp);
    ushort8 pb1 = *(const ushort8*)(Bp + 8);

    floatx4 acc[4][2];
    #pragma unroll
    for (int i = 0; i < 4; i++)
        #pragma unroll
        for (int j = 0; j < 2; j++) acc[i][j] = (floatx4){0.f, 0.f, 0.f, 0.f};

    const int nk = K >> 5;
    for (int kk = 0; kk < nk; kk++) {
        *(ushort8*)&As[sar * 40 + sac]     = pa;
        *(ushort8*)&Bs[sbr * 40 + sbc]     = pb0;
        *(ushort8*)&Bs[sbr * 40 + sbc + 8] = pb1;
        __syncthreads();
        if (kk + 1 < nk) {
            int ko = (kk + 1) * 32;
            pa  = *(const ushort8*)(Ap + ko);
            pb0 = *(const ushort8*)(Bp + ko);
            pb1 = *(const ushort8*)(Bp + ko + 8);
        }
        U8 af[4], bf[2];
        #pragma unroll
        for (int i = 0; i < 4; i++)
            af[i].u = *(const ushort8*)&As[(i * 16 + l15) * 40 + quad * 8];
        #pragma unroll
        for (int j = 0; j < 2; j++)
            bf[j].u = *(const ushort8*)&Bs[(wn + j * 16 + l15) * 40 + quad * 8];
        #pragma unroll
        for (int i = 0; i < 4; i++)
            #pragma unroll
            for (int j = 0; j < 2; j++)
                acc[i][j] = __builtin_amdgcn_mfma_f32_16x16x32_bf16(af[i].b, bf[j].b, acc[i][j], 0, 0, 0);
        __syncthreads();
    }

    #pragma unroll
    for (int i = 0; i < 4; i++) {
        #pragma unroll
        for (int j = 0; j < 2; j++) {
            int col = n0 + wn + j * 16 + l15;
            float bv = bias[col];
            #pragma unroll
            for (int r = 0; r < 4; r++) {
                int grow = m0 + i * 16 + quad * 4 + r;
                const float* R = (grow < NTOK) ? R0 : R1;
                float vv = acc[i][j][r] + bv + R[(size_t)(grow & 8191) * 256 + col];
                outF[(size_t)grow * 256 + col] = vv;
                if (outH0) outH0[(size_t)grow * 256 + col] = f2bf(vv);
                if (outH1) outH1[(size_t)grow * 512 + col] = f2bf(vv);
            }
        }
    }
}

// ---------------------------------------------------------------------------
// MFMA bf16 flash attention, S^T formulation, 128-key tiles, wave-vote
// rescale skip.  Q,K row-major [32][2048][64]; V PRE-TRANSPOSED [32][64][2048].
// KV head = bh ^ kvx.  O bf16 at row stride ldo.  qscale includes log2(e).
// ---------------------------------------------------------------------------
__global__ __launch_bounds__(256) void flash_attn(
    const unsigned short* __restrict__ Q, const unsigned short* __restrict__ K,
    const unsigned short* __restrict__ V, unsigned short* __restrict__ O,
    int ldo, int kvx, float qscale)
{
    __shared__ __align__(16) unsigned short Ks[128 * 72];   // [key][hd]
    __shared__ __align__(16) unsigned short Vt[64 * 136];   // [hd][key]

    const int t    = threadIdx.x;
    const int w    = t >> 6;
    const int lane = t & 63;
    const int quad = lane >> 4;
    const int l15  = lane & 15;
    const int bh   = blockIdx.y;
    const int kbh  = bh ^ kvx;
    const int q0   = blockIdx.x * 64;

    const unsigned short* Qb  = Q + (size_t)bh  * NN * HDIM;
    const unsigned short* Kb  = K + (size_t)kbh * NN * HDIM;
    const unsigned short* VTb = V + (size_t)kbh * NN * HDIM;   // [hd][n]

    const int krf = t >> 3, kcf = (t & 7) * 8;
    const int vrf = t >> 4, vcf = (t & 15) * 8;

    const int qrow = q0 + w * 16 + l15;
    bf16x8 qf0, qf1;
    {
        U8 r0, r1, x0, x1;
        r0.u = *(const ushort8*)&Qb[(size_t)qrow * HDIM + quad * 8];
        r1.u = *(const ushort8*)&Qb[(size_t)qrow * HDIM + 32 + quad * 8];
        #pragma unroll
        for (int j = 0; j < 8; j++) {
            x0.u[j] = f2bf(bf2f(r0.u[j]) * qscale);
            x1.u[j] = f2bf(bf2f(r1.u[j]) * qscale);
        }
        qf0 = x0.b; qf1 = x1.b;
    }

    floatx4 o[4];
    #pragma unroll
    for (int c = 0; c < 4; c++) o[c] = (floatx4){0.f, 0.f, 0.f, 0.f};
    float m = -1e30f, l = 0.f;

    ushort8 ka[4], va[4];
    #pragma unroll
    for (int i = 0; i < 4; i++) {
        ka[i] = *(const ushort8*)&Kb[(size_t)(krf + 32 * i) * HDIM + kcf];
        va[i] = *(const ushort8*)&VTb[(size_t)(vrf + 16 * i) * NN + vcf];
    }

    for (int j0 = 0; j0 < NN; j0 += 128) {
        #pragma unroll
        for (int i = 0; i < 4; i++) {
            *(ushort8*)&Ks[(krf + 32 * i) * 72 + kcf]  = ka[i];
            *(ushort8*)&Vt[(vrf + 16 * i) * 136 + vcf] = va[i];
        }
        __syncthreads();
        if (j0 + 128 < NN) {
            int jn = j0 + 128;
            #pragma unroll
            for (int i = 0; i < 4; i++) {
                ka[i] = *(const ushort8*)&Kb[(size_t)(jn + krf + 32 * i) * HDIM + kcf];
                va[i] = *(const ushort8*)&VTb[(size_t)(vrf + 16 * i) * NN + jn + vcf];
            }
        }

        floatx4 s[8];
        #pragma unroll
        for (int t8 = 0; t8 < 8; t8++) {
            U8 k0, k1;
            k0.u = *(const ushort8*)&Ks[(t8 * 16 + l15) * 72 + quad * 8];
            k1.u = *(const ushort8*)&Ks[(t8 * 16 + l15) * 72 + 32 + quad * 8];
            floatx4 z = (floatx4){0.f, 0.f, 0.f, 0.f};
            z = __builtin_amdgcn_mfma_f32_16x16x32_bf16(k0.b, qf0, z, 0, 0, 0);
            z = __builtin_amdgcn_mfma_f32_16x16x32_bf16(k1.b, qf1, z, 0, 0, 0);
            s[t8] = z;
        }

        float mx = s[0][0];
        #pragma unroll
        for (int t8 = 0; t8 < 8; t8++)
            #pragma unroll
            for (int r = 0; r < 4; r++) mx = fmaxf(mx, s[t8][r]);
        mx = fmaxf(mx, __shfl_xor(mx, 16, 64));
        mx = fmaxf(mx, __shfl_xor(mx, 32, 64));
        if (__ballot(mx > m)) {
            float mn = fmaxf(m, mx);
            float al = exp2f(m - mn);
            m = mn;
            l *= al;
            #pragma unroll
            for (int c = 0; c < 4; c++)
                #pragma unroll
                for (int r = 0; r < 4; r++) o[c][r] *= al;
        }
        float rs = 0.f;
        #pragma unroll
        for (int t8 = 0; t8 < 8; t8++)
            #pragma unroll
            for (int r = 0; r < 4; r++) {
                float p = exp2f(s[t8][r] - m);
                s[t8][r] = p;
                rs += p;
            }
        rs += __shfl_xor(rs, 16, 64);
        rs += __shfl_xor(rs, 32, 64);
        l += rs;

        short4v pf[8];
        #pragma unroll
        for (int t8 = 0; t8 < 8; t8++) {
            U4 pk;
            pk.u[0] = pkbf(s[t8][0], s[t8][1]);
            pk.u[1] = pkbf(s[t8][2], s[t8][3]);
            pf[t8] = pk.s;
        }

        #pragma unroll
        for (int c = 0; c < 4; c++) {
            #pragma unroll
            for (int t8 = 0; t8 < 8; t8++) {
                U4 vf;
                vf.l = *(const unsigned long long*)
                    &Vt[(c * 16 + l15) * 136 + t8 * 16 + quad * 4];
                o[c] = MFMA16(vf.s, pf[t8], o[c]);
            }
        }
        __syncthreads();
    }

    const int ds = bh >> 4, b = (bh >> 2) & 3, h = bh & 3;
    const int q = q0 + w * 16 + l15;
    const size_t row = (size_t)ds * NTOK + b * NN + q;
    float inv = 1.f / l;
    #pragma unroll
    for (int c = 0; c < 4; c++) {
        ushort4 pk;
        pk.x = f2bf(o[c][0] * inv);
        pk.y = f2bf(o[c][1] * inv);
        pk.z = f2bf(o[c][2] * inv);
        pk.w = f2bf(o[c][3] * inv);
        *(ushort4*)&O[row * ldo + h * HDIM + c * 16 + quad * 4] = pk;
    }
}

// ---------------------------------------------------------------------------
// LayerNorm + exact GELU, bf16 in-place, row width 512, one block per row.
// ---------------------------------------------------------------------------
__global__ __launch_bounds__(256) void ln_gelu(
    unsigned short* __restrict__ hb, const float* __restrict__ g,
    const float* __restrict__ be)
{
    __shared__ float r1[4], r2[4];
    const int t = threadIdx.x;
    const size_t row = blockIdx.x;
    unsigned short* ip = hb + row * 512;
    float x0 = bf2f(ip[t]), x1 = bf2f(ip[t + 256]);
    float s = x0 + x1, ss = x0 * x0 + x1 * x1;
    #pragma unroll
    for (int o = 32; o > 0; o >>= 1) { s += __shfl_down(s, o); ss += __shfl_down(ss, o); }
    if ((t & 63) == 0) { r1[t >> 6] = s; r2[t >> 6] = ss; }
    __syncthreads();
    float S  = r1[0] + r1[1] + r1[2] + r1[3];
    float SS = r2[0] + r2[1] + r2[2] + r2[3];
    float mean = S * (1.f / 512.f);
    float var  = SS * (1.f / 512.f) - mean * mean;
    float inv  = rsqrtf(var + 1e-5f);
    float y0 = (x0 - mean) * inv * g[t]       + be[t];
    float y1 = (x1 - mean) * inv * g[t + 256] + be[t + 256];
    ip[t]       = f2bf(0.5f * y0 * (1.f + erff(y0 * 0.70710678f)));
    ip[t + 256] = f2bf(0.5f * y1 * (1.f + erff(y1 * 0.70710678f)));
}

// ---------------------------------------------------------------------------
// cat[row][0:256] = desc (f32 pair) as bf16.
// ---------------------------------------------------------------------------
__global__ __launch_bounds__(256) void copy_to_cat(
    const float* __restrict__ s0, const float* __restrict__ s1,
    unsigned short* __restrict__ cat)
{
    int i = blockIdx.x * 256 + threadIdx.x;
    int row = i >> 6, c4 = (i & 63) * 4;
    const float* s = (row < NTOK) ? s0 : s1;
    float4 a = *(const float4*)&s[(size_t)(row & 8191) * 256 + c4];
    ushort4 p = { f2bf(a.x), f2bf(a.y), f2bf(a.z), f2bf(a.w) };
    *(ushort4*)&cat[(size_t)row * 512 + c4] = p;
}

// ---------------------------------------------------------------------------
extern "C" void kernel_launch(void* const* d_in, const int* in_sizes, int n_in,
                              void* d_out, int out_size, void* d_ws, size_t ws_size,
                              hipStream_t stream)
{
    const float* desc0 = (const float*)d_in[0];
    const float* desc1 = (const float*)d_in[1];
    const float* enc0  = (const float*)d_in[2];
    const float* enc1  = (const float*)d_in[3];
    const float* Wqkv  = (const float*)d_in[4];  const float* bqkv  = (const float*)d_in[5];
    const float* Wo_s  = (const float*)d_in[6];  const float* bo_s  = (const float*)d_in[7];
    const float* W1_s  = (const float*)d_in[8];  const float* b1_s  = (const float*)d_in[9];
    const float* g_s   = (const float*)d_in[10]; const float* be_s  = (const float*)d_in[11];
    const float* W2_s  = (const float*)d_in[12]; const float* b2_s  = (const float*)d_in[13];
    const float* Wqk_c = (const float*)d_in[14]; const float* bqk_c = (const float*)d_in[15];
    const float* Wv_c  = (const float*)d_in[16]; const float* bv_c  = (const float*)d_in[17];
    const float* Wo_c  = (const float*)d_in[18]; const float* bo_c  = (const float*)d_in[19];
    const float* W1_c  = (const float*)d_in[20]; const float* b1_c  = (const float*)d_in[21];
    const float* g_c   = (const float*)d_in[22]; const float* be_c  = (const float*)d_in[23];
    const float* W2_c  = (const float*)d_in[24]; const float* b2_c  = (const float*)d_in[25];

    char* ws = (char*)d_ws;
    unsigned short* wt  = (unsigned short*)ws;
    unsigned short* qb  = (unsigned short*)(ws + 2490368);
    unsigned short* kb  = (unsigned short*)(ws + 10878976);
    unsigned short* vb  = (unsigned short*)(ws + 27656192);         // V^T [32][64][2048]
    unsigned short* cat = (unsigned short*)(ws + 36044800);         // bf16 [16384][512]
    unsigned short* hb  = (unsigned short*)(ws + 52822016);         // bf16 [16384][512]
    unsigned short* dbf = (unsigned short*)(ws + 86376448);         // bf16 [16384][256]

    // weight regions (short offsets into wt)
    unsigned short* t_qk   = wt;                 // [512][256]: Q rows 0-255, K 256-511
    unsigned short* t_wv   = wt + 131072;        // [256][256]: V rows (h,d)
    float*          bias_s = (float*)(wt + 196608);   // 512 f32
    unsigned short* t_w1s  = wt + 197632;        // [512][512] composite
    unsigned short* t_w2s  = wt + 459776;        // [256][512]
    unsigned short* t_wqkc = wt + 590848;        // [256][256]
    unsigned short* t_wvc  = wt + 656384;        // [256][256]
    float*          bias_c = (float*)(wt + 721920);   // 512 f32
    unsigned short* t_w1c  = wt + 722944;        // [512][512] composite
    unsigned short* t_w2c  = wt + 985088;        // [256][512]

    float* outF = (float*)d_out;   // [16384][256]

    dim3 blk(256);

    // ---- prep ----
    WTab tab;
    tab.w[0] = Wqkv;  tab.o[0] = wt;     tab.K[0] = 256; tab.N[0] = 768; tab.st[0] = 256; tab.pm[0] = 1;
    tab.w[1] = W1_s;  tab.o[1] = t_w1s;  tab.K[1] = 256; tab.N[1] = 512; tab.st[1] = 512; tab.pm[1] = 0;
    tab.w[2] = W2_s;  tab.o[2] = t_w2s;  tab.K[2] = 512; tab.N[2] = 256; tab.st[2] = 512; tab.pm[2] = 0;
    tab.w[3] = Wqk_c; tab.o[3] = t_wqkc; tab.K[3] = 256; tab.N[3] = 256; tab.st[3] = 256; tab.pm[3] = 0;
    tab.w[4] = Wv_c;  tab.o[4] = t_wvc;  tab.K[4] = 256; tab.N[4] = 256; tab.st[4] = 256; tab.pm[4] = 0;
    tab.w[5] = W1_c;  tab.o[5] = t_w1c;  tab.K[5] = 256; tab.N[5] = 512; tab.st[5] = 512; tab.pm[5] = 0;
    tab.w[6] = W2_c;  tab.o[6] = t_w2c;  tab.K[6] = 512; tab.N[6] = 256; tab.st[6] = 512; tab.pm[6] = 0;
    int acc_t = 0;
    for (int s = 0; s < 7; s++) {
        tab.t0[s] = acc_t;
        acc_t += (tab.K[s] / 32) * (tab.N[s] / 32);
    }
    tab.t0[7] = acc_t;
    hipLaunchKernelGGL(wtrans, dim3(acc_t), blk, 0, stream, tab);
    hipLaunchKernelGGL(wfuse, dim3(128), blk, 0, stream,
                       Wo_s, W1_s, t_w1s, Wo_c, W1_c, t_w1c);
    hipLaunchKernelGGL(bfuse, dim3(4), blk, 0, stream,
                       bo_s, W1_s, b1_s, bias_s, bo_c, W1_c, b1_c, bias_c);

    const float QS = 0.125f * 1.44269504088896f;

    // ---- self block (both streams batched) ----
    hipLaunchKernelGGL(copy_to_cat, dim3(4096), blk, 0, stream, desc0, desc1, cat);
    // QK with fused RoPE: A=cat, B=t_qk(512 rows), mode 5
    hipLaunchKernelGGL(gemm128, dim3(4, 128), blk, 0, stream,
                       cat, 512, t_qk, 256, 256, bqkv, 5, 0,
                       qb, kb, 0, enc0, enc1);
    // V^T: A=t_wv (M=256), B=cat (N=16384), mode 0, bias[grow*3+2]
    hipLaunchKernelGGL(gemm128, dim3(128, 2), blk, 0, stream,
                       t_wv, 256, cat, 512, 256, bqkv, 0, 3,
                       vb, nullptr, 0, nullptr, nullptr);
    hipLaunchKernelGGL(flash_attn, dim3(NN / 64, 32), blk, 0, stream,
                       qb, kb, vb, cat + 256, 512, 0, QS);
    hipLaunchKernelGGL(gemm128, dim3(4, 128), blk, 0, stream,
                       cat, 512, t_w1s, 512, 512, bias_s, 1, 0,
                       hb, nullptr, 512, nullptr, nullptr);
    hipLaunchKernelGGL(ln_gelu, dim3(NTOK2), blk, 0, stream, hb, g_s, be_s);
    hipLaunchKernelGGL(gemm_w2, dim3(2, 256), blk, 0, stream,
                       hb, t_w2s, b2_s, outF, dbf, cat, desc0, desc1);

    // ---- cross block ----
    hipLaunchKernelGGL(gemm128, dim3(2, 128), blk, 0, stream,
                       dbf, 256, t_wqkc, 256, 256, bqk_c, 6, 0,
                       qb, nullptr, 0, nullptr, nullptr);
    hipLaunchKernelGGL(gemm128, dim3(128, 2), blk, 0, stream,
                       t_wvc, 256, dbf, 256, 256, bv_c, 0, 1,
                       vb, nullptr, 0, nullptr, nullptr);
    hipLaunchKernelGGL(flash_attn, dim3(NN / 64, 32), blk, 0, stream,
                       qb, qb, vb, cat + 256, 512, 16, QS);
    hipLaunchKernelGGL(gemm128, dim3(4, 128), blk, 0, stream,
                       cat, 512, t_w1c, 512, 512, bias_c, 1, 0,
                       hb, nullptr, 512, nullptr, nullptr);
    hipLaunchKernelGGL(ln_gelu, dim3(NTOK2), blk, 0, stream, hb, g_c, be_c);
    hipLaunchKernelGGL(gemm_w2, dim3(2, 256), blk, 0, stream,
                       hb, t_w2c, b2_c, outF, nullptr, nullptr,
                       outF, outF + (size_t)NTOK * 256);
}

// Round 11
// 496.283 us; speedup vs baseline: 1.0327x; 1.0327x over previous
//
#include <hip/hip_runtime.h>
#include <math.h>

#define BB 4
#define HH 4
#define NN 2048
#define DD 256
#define HDIM 64
#define NTOK 8192
#define NTOK2 16384

typedef __attribute__((ext_vector_type(8))) __bf16 bf16x8;
typedef __attribute__((ext_vector_type(8))) unsigned short ushort8;
typedef __attribute__((ext_vector_type(4))) float floatx4;
typedef __attribute__((ext_vector_type(4))) short short4v;

union U8 { ushort8 u; bf16x8 b; };
union U4 { unsigned int u[2]; unsigned long long l; short4v s; };

// v_mfma_f32_16x16x16_bf16 (K=16): A/B = 4 bf16 (short4), C/D = 4 f32.
#define MFMA16(a, b, c) __builtin_amdgcn_mfma_f32_16x16x16bf16_1k(a, b, c, 0, 0, 0)

__device__ __forceinline__ unsigned short f2bf(float x) {
    unsigned int u = __float_as_uint(x);
    u += 0x7FFF + ((u >> 16) & 1);
    return (unsigned short)(u >> 16);
}
__device__ __forceinline__ float bf2f(unsigned short u) {
    return __uint_as_float(((unsigned int)u) << 16);
}
// round-half-up bf16 pair pack (a -> low16, b -> high16); inputs >= 0
__device__ __forceinline__ unsigned int pkbf(float a, float b) {
    return ((__float_as_uint(a) + 0x8000u) >> 16) |
           ((__float_as_uint(b) + 0x8000u) & 0xFFFF0000u);
}

// ---------------------------------------------------------------------------
// Weight transpose+convert: W[K][N] f32 -> Wt[N][st] bf16.
// ---------------------------------------------------------------------------
struct WTab {
    const float* w[7];
    unsigned short* o[7];
    int K[7];
    int N[7];
    int st[7];
    int t0[8];
};

__global__ __launch_bounds__(256) void wtrans(WTab tab)
{
    __shared__ float lds[32][33];
    const int t = threadIdx.x;
    int bid = blockIdx.x;
    int s = 0;
    while (bid >= tab.t0[s + 1]) s++;
    const int ti = bid - tab.t0[s];
    const int K = tab.K[s], N = tab.N[s], st = tab.st[s];
    const int tx = ti % (N / 32), ty = ti / (N / 32);
    const int k0 = ty * 32, n0 = tx * 32;
    const float* W = tab.w[s];
    unsigned short* Wt = tab.o[s];

    {
        int r = t >> 3, c = (t & 7) * 4;
        float4 a = *(const float4*)&W[(size_t)(k0 + r) * N + n0 + c];
        lds[r][c] = a.x; lds[r][c+1] = a.y; lds[r][c+2] = a.z; lds[r][c+3] = a.w;
    }
    __syncthreads();
    {
        int n = t >> 3, kq = (t & 7) * 4;
        ushort4 p;
        p.x = f2bf(lds[kq+0][n]); p.y = f2bf(lds[kq+1][n]);
        p.z = f2bf(lds[kq+2][n]); p.w = f2bf(lds[kq+3][n]);
        *(ushort4*)&Wt[(size_t)(n0 + n) * st + k0 + kq] = p;
    }
}

// ---------------------------------------------------------------------------
// Weight fusion: Weff_bot[i][n] = sum_j Wo[i][j] * W1[256+j][n], transposed
// bf16 into out[n][256+i] (512-stride).  grid 128: seg = bid>>6.
// ---------------------------------------------------------------------------
__global__ __launch_bounds__(256) void wfuse(
    const float* __restrict__ Wo_s, const float* __restrict__ W1_s,
    unsigned short* __restrict__ o_s,
    const float* __restrict__ Wo_c, const float* __restrict__ W1_c,
    unsigned short* __restrict__ o_c)
{
    __shared__ float wo[32][33];
    __shared__ float w1[32][68];
    const int t = threadIdx.x;
    const int bid = blockIdx.x;
    const int seg = bid >> 6, ti_ = bid & 63;
    const int i0 = (ti_ >> 3) * 32, n0 = (ti_ & 7) * 64;
    const float* Wo  = seg ? Wo_c : Wo_s;
    const float* W1b = (seg ? W1_c : W1_s) + 256 * 512;
    unsigned short* out = seg ? o_c : o_s;
    const int ti = t >> 3, tn = t & 7;

    float acc[8] = {};
    for (int jc = 0; jc < 256; jc += 32) {
        {
            int r = t >> 3, c = (t & 7) * 4;
            *(float4*)&wo[r][c] = *(const float4*)&Wo[(size_t)(i0 + r) * 256 + jc + c];
            int c8 = (t & 7) * 8;
            *(float4*)&w1[r][c8]     = *(const float4*)&W1b[(size_t)(jc + r) * 512 + n0 + c8];
            *(float4*)&w1[r][c8 + 4] = *(const float4*)&W1b[(size_t)(jc + r) * 512 + n0 + c8 + 4];
        }
        __syncthreads();
        #pragma unroll
        for (int j = 0; j < 32; j++) {
            float a = wo[ti][j];
            #pragma unroll
            for (int e = 0; e < 8; e++) acc[e] += a * w1[j][tn * 8 + e];
        }
        __syncthreads();
    }
    #pragma unroll
    for (int e = 0; e < 8; e++)
        out[(size_t)(n0 + tn * 8 + e) * 512 + 256 + i0 + ti] = f2bf(acc[e]);
}

// ---------------------------------------------------------------------------
// Bias fusion: beff[n] = b1[n] + sum_j bo[j] * W1[256+j][n].  grid 4.
// ---------------------------------------------------------------------------
__global__ __launch_bounds__(256) void bfuse(
    const float* bo_s, const float* W1_s, const float* b1_s, float* bs,
    const float* bo_c, const float* W1_c, const float* b1_c, float* bc)
{
    const int seg = blockIdx.x >> 1, half = blockIdx.x & 1;
    const int n = half * 256 + threadIdx.x;
    const float* bo  = seg ? bo_c : bo_s;
    const float* W1b = (seg ? W1_c : W1_s) + 256 * 512;
    const float* b1  = seg ? b1_c : b1_s;
    float* out       = seg ? bc : bs;
    float a = b1[n];
    for (int j = 0; j < 256; j++) a += bo[j] * W1b[(size_t)j * 512 + n];
    out[n] = a;
}

// ---------------------------------------------------------------------------
// bf16 MFMA GEMM, 64x128 tile, register-staged double-buffered K-loop,
// LDS rows padded to 40 shorts.  A: m-side dual pointers (rows<8192 -> A0),
// bf16 or f32 (a_f32, converted in staging).
// modes: 1 bf16 row-major | 2 bf16 dual scatter (col<256 -> rows [bh][n][d],
//        col>=256 -> V^T [bh][d][n]) | 3 qkv scatter (V transposed) |
//        4 f32 = acc+bias+R (+ bf16 copies to outH0 [.,256] / outH1 [.,512])
// ---------------------------------------------------------------------------
__global__ __launch_bounds__(256) void gemm_mfma(
    const void* A0v, const void* A1v, int lda, int a_f32,
    const unsigned short* __restrict__ Wt, int K,
    const float* __restrict__ bias, const float* __restrict__ bias2, int mode,
    float* outF, unsigned short* outH0, unsigned short* outH1,
    unsigned short* outH2,
    int ldc, const float* R0, const float* R1)
{
    __shared__ __align__(16) unsigned short As[64 * 40];
    __shared__ __align__(16) unsigned short Bs[128 * 40];
    const int t = threadIdx.x;
    const int w = t >> 6, lane = t & 63, quad = lane >> 4, l15 = lane & 15;
    const int m0 = blockIdx.y * 64, n0 = blockIdx.x * 128;
    const int wn = w * 32;
    const int sar = t >> 2, sac = (t & 3) * 8;
    const int sbr = t >> 1, sbc = (t & 1) * 16;
    const int mside = (m0 >= 8192) ? 1 : 0;
    const int mrow = m0 & 8191;
    const unsigned short* Ah = (const unsigned short*)(mside ? A1v : A0v);
    const float* Af = (const float*)(mside ? A1v : A0v);

    const unsigned short* Bp = Wt + (size_t)(n0 + sbr) * K + sbc;

    auto loadA = [&](int ko) -> ushort8 {
        if (a_f32) {
            float4 x = *(const float4*)&Af[(size_t)(mrow + sar) * lda + ko + sac];
            float4 y = *(const float4*)&Af[(size_t)(mrow + sar) * lda + ko + sac + 4];
            ushort8 r;
            r[0] = f2bf(x.x); r[1] = f2bf(x.y); r[2] = f2bf(x.z); r[3] = f2bf(x.w);
            r[4] = f2bf(y.x); r[5] = f2bf(y.y); r[6] = f2bf(y.z); r[7] = f2bf(y.w);
            return r;
        }
        return *(const ushort8*)&Ah[(size_t)(mrow + sar) * lda + ko + sac];
    };

    ushort8 pa  = loadA(0);
    ushort8 pb0 = *(const ushort8*)(Bp);
    ushort8 pb1 = *(const ushort8*)(Bp + 8);

    floatx4 acc[4][2];
    #pragma unroll
    for (int i = 0; i < 4; i++)
        #pragma unroll
        for (int j = 0; j < 2; j++) acc[i][j] = (floatx4){0.f, 0.f, 0.f, 0.f};

    const int nk = K >> 5;
    for (int kk = 0; kk < nk; kk++) {
        *(ushort8*)&As[sar * 40 + sac]     = pa;
        *(ushort8*)&Bs[sbr * 40 + sbc]     = pb0;
        *(ushort8*)&Bs[sbr * 40 + sbc + 8] = pb1;
        __syncthreads();
        if (kk + 1 < nk) {
            int ko = (kk + 1) * 32;
            pa  = loadA(ko);
            pb0 = *(const ushort8*)(Bp + ko);
            pb1 = *(const ushort8*)(Bp + ko + 8);
        }
        U8 af[4], bf[2];
        #pragma unroll
        for (int i = 0; i < 4; i++)
            af[i].u = *(const ushort8*)&As[(i * 16 + l15) * 40 + quad * 8];
        #pragma unroll
        for (int j = 0; j < 2; j++)
            bf[j].u = *(const ushort8*)&Bs[(wn + j * 16 + l15) * 40 + quad * 8];
        #pragma unroll
        for (int i = 0; i < 4; i++)
            #pragma unroll
            for (int j = 0; j < 2; j++)
                acc[i][j] = __builtin_amdgcn_mfma_f32_16x16x32_bf16(af[i].b, bf[j].b, acc[i][j], 0, 0, 0);
        __syncthreads();
    }

    #pragma unroll
    for (int i = 0; i < 4; i++) {
        #pragma unroll
        for (int j = 0; j < 2; j++) {
            int col = n0 + wn + j * 16 + l15;
            float bv = (mode == 2 && col >= 256) ? bias2[col & 255] : bias[col];
            #pragma unroll
            for (int r = 0; r < 4; r++) {
                int grow = m0 + i * 16 + quad * 4 + r;
                float v = acc[i][j][r] + bv;
                if (mode == 1) {
                    outH0[(size_t)grow * ldc + col] = f2bf(v);
                } else if (mode == 2) {
                    int cc = col & 255;
                    int h = cc >> 6, d = cc & 63;
                    int ds = grow >> 13, b = (grow >> 11) & 3, n = grow & 2047;
                    int bh = ds * 16 + b * 4 + h;
                    if (col < 256)
                        outH0[((size_t)bh * NN + n) * HDIM + d] = f2bf(v);
                    else  // V^T layout [bh][hd][n]
                        outH1[((size_t)bh * HDIM + d) * NN + n] = f2bf(v);
                } else if (mode == 3) {
                    int sel = col % 3, cc = col / 3;
                    int h = cc >> 6, d = cc & 63;
                    int ds = grow >> 13, b = (grow >> 11) & 3, n = grow & 2047;
                    int bh = ds * 16 + b * 4 + h;
                    if (sel == 0)
                        outH0[((size_t)bh * NN + n) * HDIM + d] = f2bf(v);
                    else if (sel == 1)
                        outH1[((size_t)bh * NN + n) * HDIM + d] = f2bf(v);
                    else  // V^T layout [bh][hd][n]
                        outH2[((size_t)bh * HDIM + d) * NN + n] = f2bf(v);
                } else {
                    const float* R = (grow < NTOK) ? R0 : R1;
                    float vv = v + R[(size_t)(grow & 8191) * 256 + col];
                    outF[(size_t)grow * 256 + col] = vv;
                    if (outH0) outH0[(size_t)grow * 256 + col] = f2bf(vv);
                    if (outH1) outH1[(size_t)grow * 512 + col] = f2bf(vv);
                }
            }
        }
    }
}

// ---------------------------------------------------------------------------
// RoPE in place on kb only (bf16 [32][2048][64]); Q-rope is fused into flash.
// ---------------------------------------------------------------------------
__global__ __launch_bounds__(256) void rope_k(unsigned short* __restrict__ kb,
                                              const float* __restrict__ enc0,
                                              const float* __restrict__ enc1)
{
    int i = blockIdx.x * 256 + threadIdx.x;     // 2^21 pair slots
    int dp = (i & 31) * 2;
    int n  = (i >> 5) & (NN - 1);
    int h  = (i >> 16) & 3;
    int b  = (i >> 18) & 3;
    int ds = (i >> 20) & 1;
    unsigned short* tq = kb +
        (((size_t)(ds * 16 + b * 4 + h)) * NN + n) * HDIM + dp;
    const float* e0 = (ds ? enc1 : enc0) + ((size_t)b * NN + n) * HDIM + dp;
    const float* e1 = e0 + (size_t)BB * NN * HDIM;
    float x0 = bf2f(tq[0]), x1 = bf2f(tq[1]);
    float y0 = x0 * e0[0] - x1 * e1[0];
    float y1 = x1 * e0[1] + x0 * e1[1];
    tq[0] = f2bf(y0); tq[1] = f2bf(y1);
}

// ---------------------------------------------------------------------------
// MFMA bf16 flash attention, S^T formulation.  Q,K row-major [32][2048][64];
// V PRE-TRANSPOSED [32][64][2048].  Staging = pure b128 copies with register
// prefetch.  KV head = bh ^ kvx.  O bf16 at row stride ldo.
// Optional fused Q-RoPE (e0g/e1g) and desc->cat left-half copy (d0/d1).
// qscale includes log2(e).
// ---------------------------------------------------------------------------
__global__ __launch_bounds__(256) void flash_attn(
    const unsigned short* __restrict__ Q, const unsigned short* __restrict__ K,
    const unsigned short* __restrict__ V, unsigned short* __restrict__ O,
    int ldo, int kvx, float qscale,
    const float* __restrict__ e0g, const float* __restrict__ e1g,
    const float* __restrict__ d0, const float* __restrict__ d1)
{
    __shared__ __align__(16) unsigned short Ks[64 * 72];    // [key][hd]
    __shared__ __align__(16) unsigned short Vt[64 * 72];    // [hd][key]

    const int t    = threadIdx.x;
    const int w    = t >> 6;
    const int lane = t & 63;
    const int quad = lane >> 4;
    const int l15  = lane & 15;
    const int bh   = blockIdx.y;
    const int kbh  = bh ^ kvx;
    const int q0   = blockIdx.x * 64;
    const int ds   = bh >> 4, b = (bh >> 2) & 3, h = bh & 3;

    const unsigned short* Qb  = Q + (size_t)bh  * NN * HDIM;
    const unsigned short* Kb  = K + (size_t)kbh * NN * HDIM;
    const unsigned short* VTb = V + (size_t)kbh * NN * HDIM;   // [hd][n]

    const int srf = t >> 3, scf = (t & 7) * 8;

    // Q fragments: lane l15 = q-row, k(hd) = quad*8+j  (B-operand of K·Q^T)
    // Optional in-register RoPE: pairs (2p,2p+1) are adjacent in each chunk.
    const int qrow = q0 + w * 16 + l15;
    bf16x8 qf0, qf1;
    {
        U8 r0, r1, x0, x1;
        r0.u = *(const ushort8*)&Qb[(size_t)qrow * HDIM + quad * 8];
        r1.u = *(const ushort8*)&Qb[(size_t)qrow * HDIM + 32 + quad * 8];
        float xa[8], xb[8];
        #pragma unroll
        for (int j = 0; j < 8; j++) { xa[j] = bf2f(r0.u[j]); xb[j] = bf2f(r1.u[j]); }
        if (e0g) {
            const float* eb = ds ? e1g : e0g;
            size_t base = ((size_t)(b * NN + qrow)) * HDIM;
            const float* f0a = eb + base + quad * 8;
            const float* f1a = f0a + (size_t)BB * NN * HDIM;
            const float* f0b = eb + base + 32 + quad * 8;
            const float* f1b = f0b + (size_t)BB * NN * HDIM;
            float ya[8], yb[8];
            #pragma unroll
            for (int p = 0; p < 4; p++) {
                ya[2*p]   = xa[2*p]   * f0a[2*p]   - xa[2*p+1] * f1a[2*p];
                ya[2*p+1] = xa[2*p+1] * f0a[2*p+1] + xa[2*p]   * f1a[2*p+1];
                yb[2*p]   = xb[2*p]   * f0b[2*p]   - xb[2*p+1] * f1b[2*p];
                yb[2*p+1] = xb[2*p+1] * f0b[2*p+1] + xb[2*p]   * f1b[2*p+1];
            }
            #pragma unroll
            for (int j = 0; j < 8; j++) { xa[j] = ya[j]; xb[j] = yb[j]; }
        }
        #pragma unroll
        for (int j = 0; j < 8; j++) {
            x0.u[j] = f2bf(xa[j] * qscale);
            x1.u[j] = f2bf(xb[j] * qscale);
        }
        qf0 = x0.b; qf1 = x1.b;
    }

    floatx4 o[4];   // O^T accumulator: col = q = l15, row(hd) = c*16 + quad*4 + r
    #pragma unroll
    for (int c = 0; c < 4; c++) o[c] = (floatx4){0.f, 0.f, 0.f, 0.f};
    float m = -1e30f, l = 0.f;

    // prefetch tile 0
    ushort8 ka0 = *(const ushort8*)&Kb[(size_t)srf * HDIM + scf];
    ushort8 ka1 = *(const ushort8*)&Kb[(size_t)(srf + 32) * HDIM + scf];
    ushort8 va0 = *(const ushort8*)&VTb[(size_t)srf * NN + scf];
    ushort8 va1 = *(const ushort8*)&VTb[(size_t)(srf + 32) * NN + scf];

    for (int j0 = 0; j0 < NN; j0 += 64) {
        *(ushort8*)&Ks[srf * 72 + scf]        = ka0;
        *(ushort8*)&Ks[(srf + 32) * 72 + scf] = ka1;
        *(ushort8*)&Vt[srf * 72 + scf]        = va0;
        *(ushort8*)&Vt[(srf + 32) * 72 + scf] = va1;
        __syncthreads();
        if (j0 + 64 < NN) {
            int jn = j0 + 64;
            ka0 = *(const ushort8*)&Kb[(size_t)(jn + srf) * HDIM + scf];
            ka1 = *(const ushort8*)&Kb[(size_t)(jn + srf + 32) * HDIM + scf];
            va0 = *(const ushort8*)&VTb[(size_t)srf * NN + jn + scf];
            va1 = *(const ushort8*)&VTb[(size_t)(srf + 32) * NN + jn + scf];
        }

        // S^T = K (qscale*Q)^T : s[t4]: col = q = l15, row(key) = quad*4 + r
        floatx4 s[4];
        #pragma unroll
        for (int t4 = 0; t4 < 4; t4++) {
            U8 k0, k1;
            k0.u = *(const ushort8*)&Ks[(t4 * 16 + l15) * 72 + quad * 8];
            k1.u = *(const ushort8*)&Ks[(t4 * 16 + l15) * 72 + 32 + quad * 8];
            floatx4 z = (floatx4){0.f, 0.f, 0.f, 0.f};
            z = __builtin_amdgcn_mfma_f32_16x16x32_bf16(k0.b, qf0, z, 0, 0, 0);
            z = __builtin_amdgcn_mfma_f32_16x16x32_bf16(k1.b, qf1, z, 0, 0, 0);
            s[t4] = z;
        }

        // per-lane online softmax (one q-row per lane; keys split across quads)
        float mx = s[0][0];
        #pragma unroll
        for (int t4 = 0; t4 < 4; t4++)
            #pragma unroll
            for (int r = 0; r < 4; r++) mx = fmaxf(mx, s[t4][r]);
        mx = fmaxf(mx, __shfl_xor(mx, 16, 64));
        mx = fmaxf(mx, __shfl_xor(mx, 32, 64));
        float mn = fmaxf(m, mx);
        float al = exp2f(m - mn);
        m = mn;
        float rs = 0.f;
        #pragma unroll
        for (int t4 = 0; t4 < 4; t4++)
            #pragma unroll
            for (int r = 0; r < 4; r++) {
                float p = exp2f(s[t4][r] - mn);
                s[t4][r] = p;
                rs += p;
            }
        rs += __shfl_xor(rs, 16, 64);
        rs += __shfl_xor(rs, 32, 64);
        l = l * al + rs;
        #pragma unroll
        for (int c = 0; c < 4; c++)
            #pragma unroll
            for (int r = 0; r < 4; r++) o[c][r] *= al;

        // pack P^T fragments: C/D layout of S^T == B-operand of 16x16x16
        short4v pf[4];
        #pragma unroll
        for (int t4 = 0; t4 < 4; t4++) {
            U4 pk;
            pk.u[0] = pkbf(s[t4][0], s[t4][1]);
            pk.u[1] = pkbf(s[t4][2], s[t4][3]);
            pf[t4] = pk.s;
        }

        // O^T += V^T P^T : A = V^T chunk [hd=c*16+l15][key=t4*16+quad*4+j]
        #pragma unroll
        for (int c = 0; c < 4; c++) {
            #pragma unroll
            for (int t4 = 0; t4 < 4; t4++) {
                U4 vf;
                vf.l = *(const unsigned long long*)
                    &Vt[(c * 16 + l15) * 72 + t4 * 16 + quad * 4];
                o[c] = MFMA16(vf.s, pf[t4], o[c]);
            }
        }
        __syncthreads();
    }

    // epilogue: normalize, write bf16 at stride ldo; lane owns q=l15, 16 hd
    const int q = q0 + w * 16 + l15;
    const size_t row = (size_t)ds * NTOK + b * NN + q;
    float inv = 1.f / l;
    #pragma unroll
    for (int c = 0; c < 4; c++) {
        ushort4 pk;
        pk.x = f2bf(o[c][0] * inv);
        pk.y = f2bf(o[c][1] * inv);
        pk.z = f2bf(o[c][2] * inv);
        pk.w = f2bf(o[c][3] * inv);
        *(ushort4*)&O[row * ldo + h * HDIM + c * 16 + quad * 4] = pk;
    }
    // fused concat left-half: cat[row][h*64 + idx] = bf16(desc)
    if (d0) {
        const float* dsc = ds ? d1 : d0;
        #pragma unroll
        for (int c = 0; c < 4; c++) {
            float4 a = *(const float4*)
                &dsc[((size_t)(b * NN + q)) * 256 + h * HDIM + c * 16 + quad * 4];
            ushort4 pk = { f2bf(a.x), f2bf(a.y), f2bf(a.z), f2bf(a.w) };
            *(ushort4*)&O[row * ldo + h * HDIM + c * 16 + quad * 4 - 256] = pk;
        }
    }
}

// ---------------------------------------------------------------------------
// LayerNorm + exact GELU, bf16 in-place, row width 512, one block per row.
// ---------------------------------------------------------------------------
__global__ __launch_bounds__(256) void ln_gelu(
    unsigned short* __restrict__ hb, const float* __restrict__ g,
    const float* __restrict__ be)
{
    __shared__ float r1[4], r2[4];
    const int t = threadIdx.x;
    const size_t row = blockIdx.x;
    unsigned short* ip = hb + row * 512;
    float x0 = bf2f(ip[t]), x1 = bf2f(ip[t + 256]);
    float s = x0 + x1, ss = x0 * x0 + x1 * x1;
    #pragma unroll
    for (int o = 32; o > 0; o >>= 1) { s += __shfl_down(s, o); ss += __shfl_down(ss, o); }
    if ((t & 63) == 0) { r1[t >> 6] = s; r2[t >> 6] = ss; }
    __syncthreads();
    float S  = r1[0] + r1[1] + r1[2] + r1[3];
    float SS = r2[0] + r2[1] + r2[2] + r2[3];
    float mean = S * (1.f / 512.f);
    float var  = SS * (1.f / 512.f) - mean * mean;
    float inv  = rsqrtf(var + 1e-5f);
    float y0 = (x0 - mean) * inv * g[t]       + be[t];
    float y1 = (x1 - mean) * inv * g[t + 256] + be[t + 256];
    ip[t]       = f2bf(0.5f * y0 * (1.f + erff(y0 * 0.70710678f)));
    ip[t + 256] = f2bf(0.5f * y1 * (1.f + erff(y1 * 0.70710678f)));
}

// ---------------------------------------------------------------------------
extern "C" void kernel_launch(void* const* d_in, const int* in_sizes, int n_in,
                              void* d_out, int out_size, void* d_ws, size_t ws_size,
                              hipStream_t stream)
{
    const float* desc0 = (const float*)d_in[0];
    const float* desc1 = (const float*)d_in[1];
    const float* enc0  = (const float*)d_in[2];
    const float* enc1  = (const float*)d_in[3];
    const float* Wqkv  = (const float*)d_in[4];  const float* bqkv  = (const float*)d_in[5];
    const float* Wo_s  = (const float*)d_in[6];  const float* bo_s  = (const float*)d_in[7];
    const float* W1_s  = (const float*)d_in[8];  const float* b1_s  = (const float*)d_in[9];
    const float* g_s   = (const float*)d_in[10]; const float* be_s  = (const float*)d_in[11];
    const float* W2_s  = (const float*)d_in[12]; const float* b2_s  = (const float*)d_in[13];
    const float* Wqk_c = (const float*)d_in[14]; const float* bqk_c = (const float*)d_in[15];
    const float* Wv_c  = (const float*)d_in[16]; const float* bv_c  = (const float*)d_in[17];
    const float* Wo_c  = (const float*)d_in[18]; const float* bo_c  = (const float*)d_in[19];
    const float* W1_c  = (const float*)d_in[20]; const float* b1_c  = (const float*)d_in[21];
    const float* g_c   = (const float*)d_in[22]; const float* be_c  = (const float*)d_in[23];
    const float* W2_c  = (const float*)d_in[24]; const float* b2_c  = (const float*)d_in[25];

    char* ws = (char*)d_ws;
    unsigned short* wt  = (unsigned short*)ws;
    unsigned short* qb  = (unsigned short*)(ws + 2490368);
    unsigned short* kb  = (unsigned short*)(ws + 10878976);
    unsigned short* vb  = (unsigned short*)(ws + 27656192);         // V^T [32][64][2048]
    unsigned short* cat = (unsigned short*)(ws + 36044800);         // bf16 [16384][512]
    unsigned short* hb  = (unsigned short*)(ws + 52822016);         // bf16 [16384][512]
    unsigned short* dbf = (unsigned short*)(ws + 86376448);         // bf16 [16384][256]

    // composite-weight regions (shorts offsets into wt)
    unsigned short* t_qkv  = wt;                 // [768][256]
    float*          bias_s = (float*)(wt + 196608);   // 512 f32
    unsigned short* t_w1s  = wt + 262144;        // [512][512] composite
    unsigned short* t_w2s  = wt + 524288;        // [256][512]
    unsigned short* t_wqkc = wt + 655360;        // [512][256] (wqk rows + wv rows)
    float*          bias_c = (float*)(wt + 786432);   // 512 f32
    unsigned short* t_w1c  = wt + 851968;        // [512][512] composite
    unsigned short* t_w2c  = wt + 1114112;       // [256][512]

    float* outF = (float*)d_out;   // [16384][256]

    dim3 blk(256);

    // ---- prep: transpose/convert + weight-space Wo fusion ----
    WTab tab;
    tab.w[0] = Wqkv;  tab.o[0] = t_qkv;          tab.K[0] = 256; tab.N[0] = 768; tab.st[0] = 256;
    tab.w[1] = W1_s;  tab.o[1] = t_w1s;          tab.K[1] = 256; tab.N[1] = 512; tab.st[1] = 512;
    tab.w[2] = W2_s;  tab.o[2] = t_w2s;          tab.K[2] = 512; tab.N[2] = 256; tab.st[2] = 512;
    tab.w[3] = Wqk_c; tab.o[3] = t_wqkc;         tab.K[3] = 256; tab.N[3] = 256; tab.st[3] = 256;
    tab.w[4] = Wv_c;  tab.o[4] = t_wqkc + 65536; tab.K[4] = 256; tab.N[4] = 256; tab.st[4] = 256;
    tab.w[5] = W1_c;  tab.o[5] = t_w1c;          tab.K[5] = 256; tab.N[5] = 512; tab.st[5] = 512;
    tab.w[6] = W2_c;  tab.o[6] = t_w2c;          tab.K[6] = 512; tab.N[6] = 256; tab.st[6] = 512;
    int acc_t = 0;
    for (int s = 0; s < 7; s++) {
        tab.t0[s] = acc_t;
        acc_t += (tab.K[s] / 32) * (tab.N[s] / 32);
    }
    tab.t0[7] = acc_t;
    hipLaunchKernelGGL(wtrans, dim3(acc_t), blk, 0, stream, tab);
    hipLaunchKernelGGL(wfuse, dim3(128), blk, 0, stream,
                       Wo_s, W1_s, t_w1s, Wo_c, W1_c, t_w1c);
    hipLaunchKernelGGL(bfuse, dim3(4), blk, 0, stream,
                       bo_s, W1_s, b1_s, bias_s, bo_c, W1_c, b1_c, bias_c);

    auto gemm = [&](const void* A0, const void* A1, int lda, int a_f32,
                    const unsigned short* Wtp, int K, const float* bias,
                    const float* bias2, int Nc, int mode,
                    float* oF, unsigned short* oh0, unsigned short* oh1,
                    unsigned short* oh2, int ldc, const float* r0, const float* r1) {
        dim3 g(Nc / 128, NTOK2 / 64);
        hipLaunchKernelGGL(gemm_mfma, g, blk, 0, stream,
                           A0, A1, lda, a_f32, Wtp, K, bias, bias2, mode,
                           oF, oh0, oh1, oh2, ldc, r0, r1);
    };

    const float QS = 0.125f * 1.44269504088896f;

    // ---- self block (both streams batched) ----
    // QKV reads desc f32 directly (no copy_to_cat)
    gemm(desc0, desc1, 256, 1, t_qkv, 256, bqkv, nullptr, 768, 3,
         nullptr, qb, kb, vb, 0, nullptr, nullptr);
    hipLaunchKernelGGL(rope_k, dim3(8192), blk, 0, stream, kb, enc0, enc1);
    // flash: fused Q-RoPE + writes cat right half AND left half (desc copy)
    hipLaunchKernelGGL(flash_attn, dim3(NN / 64, 32), blk, 0, stream,
                       qb, kb, vb, cat + 256, 512, 0, QS,
                       enc0, enc1, desc0, desc1);
    gemm(cat, cat + (size_t)8192 * 512, 512, 0, t_w1s, 512, bias_s, nullptr, 512, 1,
         nullptr, hb, nullptr, nullptr, 512, nullptr, nullptr);
    hipLaunchKernelGGL(ln_gelu, dim3(NTOK2), blk, 0, stream, hb, g_s, be_s);
    gemm(hb, hb + (size_t)8192 * 512, 512, 0, t_w2s, 512, b2_s, nullptr, 256, 4,
         outF, dbf, cat, nullptr, 256, desc0, desc1);

    // ---- cross block ----
    gemm(dbf, dbf + (size_t)8192 * 256, 256, 0, t_wqkc, 256, bqk_c, bv_c, 512, 2,
         nullptr, qb, vb, nullptr, 0, nullptr, nullptr);
    hipLaunchKernelGGL(flash_attn, dim3(NN / 64, 32), blk, 0, stream,
                       qb, qb, vb, cat + 256, 512, 16, QS,
                       nullptr, nullptr, nullptr, nullptr);
    gemm(cat, cat + (size_t)8192 * 512, 512, 0, t_w1c, 512, bias_c, nullptr, 512, 1,
         nullptr, hb, nullptr, nullptr, 512, nullptr, nullptr);
    hipLaunchKernelGGL(ln_gelu, dim3(NTOK2), blk, 0, stream, hb, g_c, be_c);
    gemm(hb, hb + (size_t)8192 * 512, 512, 0, t_w2c, 512, b2_c, nullptr, 256, 4,
         outF, nullptr, nullptr, nullptr, 256, outF, outF + (size_t)NTOK * 256);
}